// Round 12
// baseline (949.417 us; speedup 1.0000x reference)
//
#include <hip/hip_runtime.h>
#include <hip/hip_bf16.h>

// B=16, M=4096, D=64, K=1024. fp32 in / fp32 out (locked R10-R11).
// Output: [z_q_st (N*D) | indices (N) | loss (1)], fp32. R11 passed absmax 0.
//
// R11 post-mortem: fp64 LDS-broadcast loop = 720us, VALUBusy 34% (fp64 chain
// latency) + LDS broadcast wall (~328us invariant). This round:
//  - codebook read DIRECTLY from global with wave-uniform address (L1/L2
//    broadcast; 256KB codebook, ~7us device-wide from L2) — no LDS hot loop.
//  - fp32 screen, 4 independent FMA chains (order free for a screen),
//    top-2 gap guard, margin 1e-2 ~ 100x worst-case fp32 chain error.
//  - flagged rows (~0.2%): wave-cooperative full-K fp64 rescan, exact
//    lexicographic (score,idx) first-min — same semantics as passing R11.
#define D_     64
#define K_     1024
#define N_     65536
#define TPB    128
#define NBLK   (N_ / TPB)    // 512 blocks
#define MARGIN 1.0e-2f

// ---------------------------------------------------------------------------
// Kernel A: ||e_k||^2 exact fp64 + fp32 copy for the screen
// ---------------------------------------------------------------------------
__global__ __launch_bounds__(256) void vq_norms(const float* __restrict__ embed,
                                                double* __restrict__ n64,
                                                float* __restrict__ n32) {
    const int k = blockIdx.x * 256 + threadIdx.x;
    const float4* e4 = (const float4*)(embed + (size_t)k * D_);
    double acc = 0.0;
#pragma unroll
    for (int q = 0; q < 16; ++q) {
        const float4 e = e4[q];
        acc = fma((double)e.x, (double)e.x, acc);
        acc = fma((double)e.y, (double)e.y, acc);
        acc = fma((double)e.z, (double)e.z, acc);
        acc = fma((double)e.w, (double)e.w, acc);
    }
    n64[k] = acc;
    n32[k] = (float)acc;
}

// ---------------------------------------------------------------------------
// Kernel B: one thread per row. fp32 4-chain screen (global broadcast reads),
// top-2 gap guard, cooperative exact-fp64 rescan for near-ties.
// ---------------------------------------------------------------------------
__global__ __launch_bounds__(TPB) void vq_main(const float* __restrict__ z_e,
                                               const float* __restrict__ embed,
                                               const float* __restrict__ n32,
                                               const double* __restrict__ n64,
                                               float* __restrict__ out,
                                               float* __restrict__ partials) {
    __shared__ float red[TPB];

    const int tid = threadIdx.x;
    const int row = blockIdx.x * TPB + tid;

    // Row of z_e -> registers
    float xv[D_];
    {
        const float4* xg = (const float4*)(z_e + (size_t)row * D_);
#pragma unroll
        for (int q = 0; q < 16; ++q) {
            const float4 x = xg[q];
            xv[q * 4 + 0] = x.x; xv[q * 4 + 1] = x.y;
            xv[q * 4 + 2] = x.z; xv[q * 4 + 3] = x.w;
        }
    }

    // fp32 screen: wave-uniform embed reads (broadcast via L1/L2).
    float b1 = 3.4e38f, b2 = 3.4e38f;
    int   i1 = 0;
#pragma unroll 2
    for (int k = 0; k < K_; ++k) {
        const float4* ev = (const float4*)(embed + (size_t)k * D_);
        float a0 = 0.f, a1 = 0.f, a2 = 0.f, a3 = 0.f;   // 4 chains of ILP
#pragma unroll
        for (int q = 0; q < 16; ++q) {
            const float4 e = ev[q];
            a0 = fmaf(xv[q * 4 + 0], e.x, a0);
            a1 = fmaf(xv[q * 4 + 1], e.y, a1);
            a2 = fmaf(xv[q * 4 + 2], e.z, a2);
            a3 = fmaf(xv[q * 4 + 3], e.w, a3);
        }
        const float s = fmaf(-2.0f, (a0 + a1) + (a2 + a3), n32[k]);
        // Ascending k + strict < : first-minimum semantics for the screen.
        if (s < b1)      { b2 = b1; b1 = s; i1 = k; }
        else if (s < b2) { b2 = s; }
    }

    // Near-tie rows: wave-cooperative EXACT fp64 full-K rescan (rare).
    // Lexicographic (score, idx) min == np.argmin first-minimum, ground truth.
    {
        const int lane = tid & 63;
        unsigned long long mask = __ballot(b2 - b1 < MARGIN);
        while (mask) {
            const int src = __ffsll((long long)mask) - 1;
            mask &= mask - 1;
            double bs = 1.0e300; int bi = 1 << 30;
            for (int c0 = 0; c0 < K_; c0 += 64) {
                const int c = c0 + lane;
                const float* ep = embed + (size_t)c * D_;
                double dot = 0.0;
#pragma unroll
                for (int j = 0; j < D_; ++j) {
                    const float xj = __shfl(xv[j], src);   // broadcast row x
                    dot = fma((double)xj, (double)ep[j], dot);
                }
                const double s = fma(-2.0, dot, n64[c]);
                if (s < bs) { bs = s; bi = c; }
            }
#pragma unroll
            for (int off = 32; off > 0; off >>= 1) {       // (s,idx) lex-min
                const double so = __shfl_xor(bs, off);
                const int    io = __shfl_xor(bi, off);
                if (so < bs || (so == bs && io < bi)) { bs = so; bi = io; }
            }
            if (lane == src) i1 = bi;
        }
    }

    int bidx = i1 & (K_ - 1);   // defensive: gather always in-bounds

    // Epilogue (verbatim from passing R11): z_q_st = z_e + (z_q - z_e)
    const float4* eg = (const float4*)(embed + (size_t)bidx * D_);
    float4* o0 = (float4*)(out + (size_t)row * D_);
    float sq = 0.f;
#pragma unroll
    for (int q = 0; q < 16; ++q) {
        const float4 e = eg[q];
        const float d0 = e.x - xv[q * 4 + 0];
        const float d1 = e.y - xv[q * 4 + 1];
        const float d2 = e.z - xv[q * 4 + 2];
        const float d3 = e.w - xv[q * 4 + 3];
        sq = fmaf(d0, d0, sq); sq = fmaf(d1, d1, sq);
        sq = fmaf(d2, d2, sq); sq = fmaf(d3, d3, sq);
        float4 o;
        o.x = xv[q * 4 + 0] + d0;
        o.y = xv[q * 4 + 1] + d1;
        o.z = xv[q * 4 + 2] + d2;
        o.w = xv[q * 4 + 3] + d3;
        o0[q] = o;
    }
    out[(size_t)N_ * D_ + row] = (float)bidx;

    // Block loss reduction
    red[tid] = sq;
    __syncthreads();
#pragma unroll
    for (int s = TPB / 2; s > 0; s >>= 1) {
        if (tid < s) red[tid] += red[tid + s];
        __syncthreads();
    }
    if (tid == 0) partials[blockIdx.x] = red[0];
}

// ---------------------------------------------------------------------------
// Kernel C: reduce NBLK partials -> vq_loss = 1.25 * mean(sqdiff), fp32
// ---------------------------------------------------------------------------
__global__ __launch_bounds__(TPB) void vq_loss_final(const float* __restrict__ partials,
                                                     float* __restrict__ out) {
    __shared__ float red[TPB];
    const int tid = threadIdx.x;
    float s = 0.f;
#pragma unroll
    for (int i = 0; i < NBLK / TPB; ++i) s += partials[tid + i * TPB];
    red[tid] = s;
    __syncthreads();
#pragma unroll
    for (int w = TPB / 2; w > 0; w >>= 1) {
        if (tid < w) red[tid] += red[tid + w];
        __syncthreads();
    }
    if (tid == 0)
        out[(size_t)N_ * D_ + N_] = 1.25f * red[0] / (float)((size_t)N_ * D_);
}

// ---------------------------------------------------------------------------
extern "C" void kernel_launch(void* const* d_in, const int* in_sizes, int n_in,
                              void* d_out, int out_size, void* d_ws, size_t ws_size,
                              hipStream_t stream) {
    const float* z_e;
    const float* embed;
    if (in_sizes[0] == N_ * D_) {
        z_e   = (const float*)d_in[0];
        embed = (const float*)d_in[1];
    } else {
        z_e   = (const float*)d_in[1];
        embed = (const float*)d_in[0];
    }
    float* out = (float*)d_out;

    double* n64      = (double*)d_ws;       // 8 KB
    float*  n32      = (float*)(n64 + K_);  // 4 KB
    float*  partials = n32 + K_;            // 2 KB

    vq_norms<<<K_ / 256, 256, 0, stream>>>(embed, n64, n32);
    vq_main<<<NBLK, TPB, 0, stream>>>(z_e, embed, n32, n64, out, partials);
    vq_loss_final<<<1, TPB, 0, stream>>>(partials, out);
}

// Round 13
// 398.443 us; speedup vs baseline: 2.3828x; 2.3828x over previous
//
#include <hip/hip_runtime.h>
#include <hip/hip_bf16.h>

// B=16, M=4096, D=64, K=1024. fp32 in / fp32 out (locked R10-R11).
// Output: [z_q_st (N*D) | indices (N) | loss (1)], fp32.
//
// R12 post-mortem: global wave-uniform codebook reads = ~200cyc L2 latency on
// a dependent loop at 1 wave/SIMD -> VALUBusy 8%, 902us. Back to LDS tiles.
// R13: fp32 screen + 4-way K-split per row (4 thr/row): 4x waves/CU (16),
// 4x fewer LDS instr/lane, LDS code stride padded to 68 floats so the quad's
// 4 concurrent addresses hit disjoint bank quartets. Exactness: merged top-2
// gap < MARGIN -> wave-cooperative exact fp64 rescan (R12-proven code).
#define D_     64
#define K_     1024
#define N_     65536
#define TK     128            // codes per LDS tile
#define STRIDE 68             // padded floats per code (68%32=4 -> bank shift)
#define TPB    256            // 64 rows x 4 threads/row
#define RPB    64
#define NBLK   (N_ / RPB)     // 1024 blocks
#define MARGIN 1.0e-2f        // fp32 screen err ~1e-4 worst case; 100x safety

// ---------------------------------------------------------------------------
// Kernel A: ||e_k||^2 exact fp64 + fp32 copy for the screen
// ---------------------------------------------------------------------------
__global__ __launch_bounds__(256) void vq_norms(const float* __restrict__ embed,
                                                double* __restrict__ n64,
                                                float* __restrict__ n32) {
    const int k = blockIdx.x * 256 + threadIdx.x;
    const float4* e4 = (const float4*)(embed + (size_t)k * D_);
    double acc = 0.0;
#pragma unroll
    for (int q = 0; q < 16; ++q) {
        const float4 e = e4[q];
        acc = fma((double)e.x, (double)e.x, acc);
        acc = fma((double)e.y, (double)e.y, acc);
        acc = fma((double)e.z, (double)e.z, acc);
        acc = fma((double)e.w, (double)e.w, acc);
    }
    n64[k] = acc;
    n32[k] = (float)acc;
}

// ---------------------------------------------------------------------------
// Kernel B: 4 threads per row; fp32 screen over padded LDS tiles; quad top-2
// merge; cooperative exact-fp64 rescan for near-ties; split epilogue.
// ---------------------------------------------------------------------------
__global__ __launch_bounds__(TPB) void vq_main(const float* __restrict__ z_e,
                                               const float* __restrict__ embed,
                                               const float* __restrict__ n32,
                                               const double* __restrict__ n64,
                                               float* __restrict__ out,
                                               float* __restrict__ partials) {
    __shared__ float lds_e[TK * STRIDE];   // 34 KB padded code tile
    __shared__ float lds_n[TK];
    __shared__ float red[TPB];

    const int tid  = threadIdx.x;
    const int p    = tid & 3;              // parity: which k mod 4 this lane scans
    const int row  = blockIdx.x * RPB + (tid >> 2);
    const int lane = tid & 63;

    // Row of z_e -> registers (all 4 quad lanes hold the same row)
    float xv[D_];
    {
        const float4* xg = (const float4*)(z_e + (size_t)row * D_);
#pragma unroll
        for (int q = 0; q < 16; ++q) {
            const float4 x = xg[q];
            xv[q * 4 + 0] = x.x; xv[q * 4 + 1] = x.y;
            xv[q * 4 + 2] = x.z; xv[q * 4 + 3] = x.w;
        }
    }

    float b1 = 3.4e38f, b2 = 3.4e38f;
    int   i1 = 0;

    for (int kt = 0; kt < K_; kt += TK) {
        __syncthreads();
        {   // stage TK codes into padded LDS: 2048 float4, 8 per thread
            const float4* esrc = (const float4*)(embed + (size_t)kt * D_);
#pragma unroll
            for (int i = 0; i < (TK * D_ / 4) / TPB; ++i) {
                const int fidx = tid + i * TPB;        // float4 index in tile
                const int c = fidx >> 4, q = fidx & 15;
                *(float4*)(lds_e + c * STRIDE + q * 4) = esrc[fidx];
            }
            if (tid < TK) lds_n[tid] = n32[kt + tid];
        }
        __syncthreads();

        // Lane scans codes kt+p, kt+p+4, ... (ascending within parity).
        // Quad's 4 addresses differ by 68 words -> bank shift 4 -> disjoint
        // bank quartets; 16-lane same-address broadcast is free.
#pragma unroll 2
        for (int j = 0; j < TK / 4; ++j) {
            const int kl = 4 * j + p;
            const float4* ev = (const float4*)(lds_e + kl * STRIDE);
            float a0 = 0.f, a1 = 0.f, a2 = 0.f, a3 = 0.f;
#pragma unroll
            for (int q = 0; q < 16; ++q) {
                const float4 e = ev[q];
                a0 = fmaf(xv[q * 4 + 0], e.x, a0);
                a1 = fmaf(xv[q * 4 + 1], e.y, a1);
                a2 = fmaf(xv[q * 4 + 2], e.z, a2);
                a3 = fmaf(xv[q * 4 + 3], e.w, a3);
            }
            const float s = fmaf(-2.0f, (a0 + a1) + (a2 + a3), lds_n[kl]);
            const int   ki = kt + kl;
            if (s < b1)      { b2 = b1; b1 = s; i1 = ki; }
            else if (s < b2) { b2 = s; }
        }
    }

    // Merge quad top-2 (lex (score,idx) => first-minimum preserved).
#pragma unroll
    for (int off = 1; off <= 2; off <<= 1) {
        const float ob1 = __shfl_xor(b1, off);
        const float ob2 = __shfl_xor(b2, off);
        const int   oi1 = __shfl_xor(i1, off);
        if (ob1 < b1 || (ob1 == b1 && oi1 < i1)) {
            b2 = fminf(b1, ob2); b1 = ob1; i1 = oi1;
        } else {
            b2 = fminf(ob1, b2);
        }
    }

    // Near-tie rows: wave-cooperative EXACT fp64 full-K rescan (rare).
    {
        unsigned long long mask = __ballot((p == 0) && (b2 - b1 < MARGIN));
        while (mask) {
            const int src = __ffsll((long long)mask) - 1;
            mask &= mask - 1;
            double bs = 1.0e300; int bi = 1 << 30;
            for (int c0 = 0; c0 < K_; c0 += 64) {
                const int c = c0 + lane;
                const float* ep = embed + (size_t)c * D_;
                double dot = 0.0;
#pragma unroll
                for (int jj = 0; jj < D_; ++jj) {
                    const float xj = __shfl(xv[jj], src);   // broadcast row x
                    dot = fma((double)xj, (double)ep[jj], dot);
                }
                const double s = fma(-2.0, dot, n64[c]);
                if (s < bs) { bs = s; bi = c; }
            }
#pragma unroll
            for (int off = 32; off > 0; off >>= 1) {        // (s,idx) lex-min
                const double so = __shfl_xor(bs, off);
                const int    io = __shfl_xor(bi, off);
                if (so < bs || (so == bs && io < bi)) { bs = so; bi = io; }
            }
            if (lane == src) i1 = bi;
        }
    }

    // Broadcast final index from quad leader; clamp for safe gather.
    int bidx = __shfl(i1, lane & ~3) & (K_ - 1);

    // Split epilogue: lane m of the quad handles 16 of the row's 64 floats.
    const float4* eg = (const float4*)(embed + (size_t)bidx * D_) + p * 4;
    float4*       o0 = (float4*)(out + (size_t)row * D_) + p * 4;
    float sq = 0.f;
#pragma unroll
    for (int q = 0; q < 4; ++q) {
        const float4 e = eg[q];
        const int   x0 = p * 16 + q * 4;
        const float d0 = e.x - xv[x0 + 0];
        const float d1 = e.y - xv[x0 + 1];
        const float d2 = e.z - xv[x0 + 2];
        const float d3 = e.w - xv[x0 + 3];
        sq = fmaf(d0, d0, sq); sq = fmaf(d1, d1, sq);
        sq = fmaf(d2, d2, sq); sq = fmaf(d3, d3, sq);
        float4 o;
        o.x = xv[x0 + 0] + d0;
        o.y = xv[x0 + 1] + d1;
        o.z = xv[x0 + 2] + d2;
        o.w = xv[x0 + 3] + d3;
        o0[q] = o;
    }
    if (p == 0) out[(size_t)N_ * D_ + row] = (float)bidx;

    // Block loss reduction (each element counted exactly once)
    red[tid] = sq;
    __syncthreads();
#pragma unroll
    for (int s = TPB / 2; s > 0; s >>= 1) {
        if (tid < s) red[tid] += red[tid + s];
        __syncthreads();
    }
    if (tid == 0) partials[blockIdx.x] = red[0];
}

// ---------------------------------------------------------------------------
// Kernel C: reduce NBLK partials -> vq_loss = 1.25 * mean(sqdiff), fp32
// ---------------------------------------------------------------------------
__global__ __launch_bounds__(256) void vq_loss_final(const float* __restrict__ partials,
                                                     float* __restrict__ out) {
    __shared__ float red[256];
    const int tid = threadIdx.x;
    float s = 0.f;
#pragma unroll
    for (int i = 0; i < NBLK / 256; ++i) s += partials[tid + i * 256];
    red[tid] = s;
    __syncthreads();
#pragma unroll
    for (int w = 128; w > 0; w >>= 1) {
        if (tid < w) red[tid] += red[tid + w];
        __syncthreads();
    }
    if (tid == 0)
        out[(size_t)N_ * D_ + N_] = 1.25f * red[0] / (float)((size_t)N_ * D_);
}

// ---------------------------------------------------------------------------
extern "C" void kernel_launch(void* const* d_in, const int* in_sizes, int n_in,
                              void* d_out, int out_size, void* d_ws, size_t ws_size,
                              hipStream_t stream) {
    const float* z_e;
    const float* embed;
    if (in_sizes[0] == N_ * D_) {
        z_e   = (const float*)d_in[0];
        embed = (const float*)d_in[1];
    } else {
        z_e   = (const float*)d_in[1];
        embed = (const float*)d_in[0];
    }
    float* out = (float*)d_out;

    double* n64      = (double*)d_ws;       // 8 KB
    float*  n32      = (float*)(n64 + K_);  // 4 KB
    float*  partials = n32 + K_;            // 4 KB

    vq_norms<<<K_ / 256, 256, 0, stream>>>(embed, n64, n32);
    vq_main<<<NBLK, TPB, 0, stream>>>(z_e, embed, n32, n64, out, partials);
    vq_loss_final<<<1, 256, 0, stream>>>(partials, out);
}